// Round 2
// baseline (817.571 us; speedup 1.0000x reference)
//
#include <hip/hip_runtime.h>

#define NN 10000
#define NE 160000

typedef unsigned short u16;
typedef __bf16 bf16x8 __attribute__((ext_vector_type(8)));
typedef float f32x4 __attribute__((ext_vector_type(4)));

#define INV_SQRT3 0.57735026918962576451f
#define INV_SQRT2 0.70710678118654752440f
#define LIN_SCALE 0.08838834764831845f

// ws layout
#define H3_OFF    0                  // E*64 bf16 = 20,480,000 B
#define WM4_OFF   20480000           // 40960 u16 = 81,920 B
#define WSW_OFF   20561920           // 4 * 16384 u16 = 131,072 B
#define CNT_OFF   20692992           // 10240 int
#define ROFF_OFF  20733952           // 10001 int (padded)
#define CUR_OFF   20774912           // 10000 int (padded)
#define EL_OFF    20815872           // 160000 int -> end 21,455,872 B

__device__ __forceinline__ u16 f2bf(float f){
  union { float f; unsigned u; } v; v.f = f;
  unsigned r = v.u + 0x7fffu + ((v.u >> 16) & 1u);
  return (u16)(r >> 16);
}
__device__ __forceinline__ float silu_f(float x){
  return x / (1.f + __expf(-x));
}

union Frag { uint4 u4; bf16x8 bf; };

// ---------------------------------------------------------------- P0: weight swizzle (fp32 -> bf16 B-fragments)
__global__ __launch_bounds__(256) void prep_weights(
    const float* __restrict__ Wm4, const float* __restrict__ rW0, const float* __restrict__ rW1,
    const float* __restrict__ sW0, const float* __restrict__ sW1,
    u16* __restrict__ wm4s, u16* __restrict__ wsw){
  int t  = blockIdx.x * blockDim.x + threadIdx.x;
  int nt = gridDim.x * blockDim.x;
  for (int idx = t; idx < 40960; idx += nt){           // Wm4: (64,640), 40 ct x 2 ks
    int jj = idx & 7; int lane = (idx >> 3) & 63; int blk = idx >> 9;
    int ks = blk & 1; int ct = blk >> 1;
    int k = ks*32 + ((lane >> 4) << 3) + jj;
    int col = ct*16 + (lane & 15);
    wm4s[idx] = f2bf(Wm4[k*640 + col]);
  }
  const float* Ws[4] = { rW0, rW1, sW0, sW1 };
  for (int m = 0; m < 4; ++m){
    const float* src = Ws[m];
    u16* dst = wsw + m*16384;
    for (int idx = t; idx < 16384; idx += nt){         // (128,128), 8 ct x 4 ks
      int jj = idx & 7; int lane = (idx >> 3) & 63; int blk = idx >> 9;
      int ks = blk & 3; int ct = blk >> 2;
      int k = ks*32 + ((lane >> 4) << 3) + jj;
      int col = ct*16 + (lane & 15);
      dst[idx] = f2bf(src[k*128 + col]);
    }
  }
}

// ---------------------------------------------------------------- CSR build (counting sort by receiver)
__global__ __launch_bounds__(256) void csr_zero(int* __restrict__ cnt){
  int t = blockIdx.x * blockDim.x + threadIdx.x;
  if (t < 10240) cnt[t] = 0;
}

__global__ __launch_bounds__(256) void csr_count(const int* __restrict__ rcv, int* __restrict__ cnt){
  int e = blockIdx.x * blockDim.x + threadIdx.x;
  if (e < NE) atomicAdd(&cnt[rcv[e]], 1);
}

__global__ __launch_bounds__(256) void csr_scan(const int* __restrict__ cnt,
                                                int* __restrict__ roff, int* __restrict__ cur){
  __shared__ int s_part[256];
  int t = threadIdx.x;
  int base = t * 40;                      // 256*40 = 10240 >= NN
  int local = 0;
  for (int i = 0; i < 40; ++i){
    int idx = base + i;
    local += (idx < NN) ? cnt[idx] : 0;
  }
  s_part[t] = local;
  __syncthreads();
  for (int d = 1; d < 256; d <<= 1){      // inclusive Hillis-Steele
    int v = (t >= d) ? s_part[t - d] : 0;
    __syncthreads();
    s_part[t] += v;
    __syncthreads();
  }
  int run = (t == 0) ? 0 : s_part[t - 1];
  for (int i = 0; i < 40; ++i){
    int idx = base + i;
    if (idx < NN){
      roff[idx] = run;
      cur[idx]  = run;
      run += cnt[idx];
    }
  }
  if (t == 0) roff[NN] = NE;
}

__global__ __launch_bounds__(256) void csr_scatter(const int* __restrict__ rcv,
                                                   int* __restrict__ cur, int* __restrict__ elist){
  int e = blockIdx.x * blockDim.x + threadIdx.x;
  if (e < NE){
    int r = rcv[e];
    int p = atomicAdd(&cur[r], 1);
    elist[p] = e;
  }
}

// ---------------------------------------------------------------- K1: h3 = silu(silu(silu(e@Wm1)@Wm2)@Wm3), bf16 out
__global__ __launch_bounds__(256) void radial_h3_kernel(
    const float* __restrict__ emb, const float* __restrict__ Wm1,
    const float* __restrict__ Wm2, const float* __restrict__ Wm3,
    u16* __restrict__ h3){
  __shared__ float s_emb[64*12];
  __shared__ float s_w1[8*64];
  __shared__ float s_w2[64*68];
  __shared__ float s_w3[64*68];
  __shared__ float s_ha[64*65];
  __shared__ float s_hb[64*65];
  int t = threadIdx.x;
  int e0 = blockIdx.x * 64;
  if (t < 64){
    const float4* src = (const float4*)(emb + (size_t)(e0 + t)*8);
    float4 v0 = src[0], v1 = src[1];
    float* r = s_emb + t*12;
    r[0]=v0.x; r[1]=v0.y; r[2]=v0.z; r[3]=v0.w;
    r[4]=v1.x; r[5]=v1.y; r[6]=v1.z; r[7]=v1.w;
  }
  for (int idx = t; idx < 512; idx += 256) s_w1[idx] = Wm1[idx];
  for (int idx = t; idx < 4096; idx += 256){
    int k = idx >> 6, d = idx & 63;
    s_w2[k*68 + d] = Wm2[idx];
    s_w3[k*68 + d] = Wm3[idx];
  }
  __syncthreads();
  int p  = t >> 3;       // 0..31 -> edges 2p, 2p+1
  int dg = t & 7;        // outputs dg*8 .. dg*8+7
  int ea = 2*p, eb = 2*p + 1;
  float acc0[8], acc1[8];
  // layer 1 (K=8)
  #pragma unroll
  for (int j = 0; j < 8; ++j){ acc0[j]=0.f; acc1[j]=0.f; }
  #pragma unroll
  for (int k = 0; k < 8; ++k){
    float h0 = s_emb[ea*12 + k], h1 = s_emb[eb*12 + k];
    #pragma unroll
    for (int j = 0; j < 8; ++j){
      float wv = s_w1[k*64 + dg*8 + j];
      acc0[j] = fmaf(h0, wv, acc0[j]); acc1[j] = fmaf(h1, wv, acc1[j]);
    }
  }
  #pragma unroll
  for (int j = 0; j < 8; ++j){
    s_ha[ea*65 + dg*8 + j] = silu_f(acc0[j]);
    s_ha[eb*65 + dg*8 + j] = silu_f(acc1[j]);
  }
  __syncthreads();
  // layer 2 (K=64)
  #pragma unroll
  for (int j = 0; j < 8; ++j){ acc0[j]=0.f; acc1[j]=0.f; }
  #pragma unroll 4
  for (int k = 0; k < 64; ++k){
    float h0 = s_ha[ea*65 + k], h1 = s_ha[eb*65 + k];
    float wv[8];
    *(f32x4*)&wv[0] = *(const f32x4*)&s_w2[k*68 + dg*8];
    *(f32x4*)&wv[4] = *(const f32x4*)&s_w2[k*68 + dg*8 + 4];
    #pragma unroll
    for (int j = 0; j < 8; ++j){
      acc0[j] = fmaf(h0, wv[j], acc0[j]); acc1[j] = fmaf(h1, wv[j], acc1[j]);
    }
  }
  #pragma unroll
  for (int j = 0; j < 8; ++j){
    s_hb[ea*65 + dg*8 + j] = silu_f(acc0[j]);
    s_hb[eb*65 + dg*8 + j] = silu_f(acc1[j]);
  }
  __syncthreads();
  // layer 3 (K=64) -> global bf16
  #pragma unroll
  for (int j = 0; j < 8; ++j){ acc0[j]=0.f; acc1[j]=0.f; }
  #pragma unroll 4
  for (int k = 0; k < 64; ++k){
    float h0 = s_hb[ea*65 + k], h1 = s_hb[eb*65 + k];
    float wv[8];
    *(f32x4*)&wv[0] = *(const f32x4*)&s_w3[k*68 + dg*8];
    *(f32x4*)&wv[4] = *(const f32x4*)&s_w3[k*68 + dg*8 + 4];
    #pragma unroll
    for (int j = 0; j < 8; ++j){
      acc0[j] = fmaf(h0, wv[j], acc0[j]); acc1[j] = fmaf(h1, wv[j], acc1[j]);
    }
  }
  union { u16 s[8]; uint4 v; } o0, o1;
  #pragma unroll
  for (int j = 0; j < 8; ++j){
    o0.s[j] = f2bf(silu_f(acc0[j]));
    o1.s[j] = f2bf(silu_f(acc1[j]));
  }
  *(uint4*)(h3 + (size_t)(e0 + ea)*64 + dg*8) = o0.v;
  *(uint4*)(h3 + (size_t)(e0 + eb)*64 + dg*8) = o1.v;
}

// ---------------------------------------------------------------- K2: per-receiver gather (zero atomics)
// one block = one node; batches of <=16 incident edges; w-GEMM via MFMA; messages to LDS;
// column-reduce into registers; single coalesced row store.
__global__ __launch_bounds__(256) void edge_msg_gather(
    const float* __restrict__ nf, const float* __restrict__ ef, const float* __restrict__ attrs,
    const int* __restrict__ snd, const u16* __restrict__ h3, const u16* __restrict__ wm4s,
    const int* __restrict__ roff, const int* __restrict__ elist, float* __restrict__ out){
  __shared__ float s_w[16*650];     // w (16 edges x 640), stride 650 spreads banks across row-groups
  __shared__ float s_m[16*520];     // messages (16 edges x 512), stride 520
  __shared__ float s_pr[512];       // receiver row (shared by all edges of this node)
  __shared__ int   s_eid[16];
  int t = threadIdx.x;
  int lane = t & 63, wave = t >> 6;
  int node = blockIdx.x;
  int beg = roff[node], end = roff[node + 1];
  int deg = end - beg;
  for (int i = t; i < 512; i += 256) s_pr[i] = nf[(size_t)node*512 + i];
  float acc0 = 0.f, acc1 = 0.f;
  int er = t >> 4, l16 = t & 15;
  int colb = lane & 15;
  int rowb = (lane >> 4) << 2;
  for (int b0 = 0; b0 < deg; b0 += 16){
    int nb = min(16, deg - b0);
    if (t < 16) s_eid[t] = elist[beg + b0 + ((t < nb) ? t : (nb - 1))];
    __syncthreads();
    // w-GEMM: w[16][640] = h3_tile[16][64] @ Wm4[64][640]
    int ea = s_eid[lane & 15];
    const u16* h3r = h3 + (size_t)ea*64 + ((lane >> 4) << 3);
    Frag a0f, a1f;
    a0f.u4 = *(const uint4*)(h3r);
    a1f.u4 = *(const uint4*)(h3r + 32);
    #pragma unroll
    for (int i = 0; i < 10; ++i){
      int ct = wave*10 + i;
      const u16* bp = wm4s + ((size_t)ct*128 + lane)*8;
      Frag b0f, b1f;
      b0f.u4 = *(const uint4*)(bp);
      b1f.u4 = *(const uint4*)(bp + 512);
      f32x4 acc = {0.f,0.f,0.f,0.f};
      acc = __builtin_amdgcn_mfma_f32_16x16x32_bf16(a0f.bf, b0f.bf, acc, 0, 0, 0);
      acc = __builtin_amdgcn_mfma_f32_16x16x32_bf16(a1f.bf, b1f.bf, acc, 0, 0, 0);
      int cb = ct*16 + colb;
      #pragma unroll
      for (int r = 0; r < 4; ++r) s_w[(rowb + r)*650 + cb] = acc[r];
    }
    __syncthreads();
    // messages: group er handles edge s_eid[er] (er < nb)
    if (er < nb){
      int eg = s_eid[er];
      int si = snd[eg];
      float4 at = *(const float4*)(attrs + (size_t)eg*4);
      float sh0 = at.x, s1x = at.y, s1y = at.z, s1z = at.w;
      const float* ps = nf + (size_t)si*512;
      const float* pe = ef + (size_t)eg*512;
      const float* wr = s_w + er*650;
      float* mr = s_m + er*520;
      #pragma unroll
      for (int j = 0; j < 8; ++j){
        int c = j*16 + l16;
        float x0 = ps[c] + s_pr[c] + pe[c];
        int vb = 128 + 3*c;
        float xa = ps[vb]   + s_pr[vb]   + pe[vb];
        float xv = ps[vb+1] + s_pr[vb+1] + pe[vb+1];
        float xc = ps[vb+2] + s_pr[vb+2] + pe[vb+2];
        float w0 = wr[c], w1 = wr[128 + c], w2 = wr[256 + c], w3 = wr[384 + c], w4 = wr[512 + c];
        float dot = xa*s1x + xv*s1y + xc*s1z;
        float m0 = w0*x0*sh0 + w1*dot*INV_SQRT3;
        float cr0 = xv*s1z - xc*s1y;
        float cr1 = xc*s1x - xa*s1z;
        float cr2 = xa*s1y - xv*s1x;
        mr[c]      = m0;
        mr[vb]     = w2*xa*sh0 + w3*x0*s1x + w4*cr0*INV_SQRT2;
        mr[vb + 1] = w2*xv*sh0 + w3*x0*s1y + w4*cr1*INV_SQRT2;
        mr[vb + 2] = w2*xc*sh0 + w3*x0*s1z + w4*cr2*INV_SQRT2;
      }
    }
    __syncthreads();
    // reduce nb message rows into per-thread accumulators (thread t owns cols t, t+256)
    for (int r = 0; r < nb; ++r){
      acc0 += s_m[r*520 + t];
      acc1 += s_m[r*520 + t + 256];
    }
    __syncthreads();   // before next batch overwrites s_eid/s_w/s_m
  }
  out[(size_t)node*512 + t]       = acc0;
  out[(size_t)node*512 + t + 256] = acc1;
}

// ---------------------------------------------------------------- K3: out = agg + EL(agg,res) + EL(nf,skip); agg IS out (in-place)
__global__ __launch_bounds__(256) void out_kernel(
    const float* __restrict__ nf, const u16* __restrict__ wsw, float* __restrict__ out){
  __shared__ u16 s_a0[16*136];
  __shared__ u16 s_a1[3][16*136];
  __shared__ u16 s_n0[16*136];
  __shared__ u16 s_n1[3][16*136];
  int t = threadIdx.x;
  int lane = t & 63, wave = t >> 6;
  int n0b = blockIdx.x << 4;
  int nr = t >> 4, l16 = t & 15;
  int node = n0b + nr;
  const float* arow = out + (size_t)node*512;
  const float* nrow = nf  + (size_t)node*512;
  #pragma unroll
  for (int jj = 0; jj < 8; ++jj){
    int c = l16 + jj*16;
    s_a0[nr*136 + c] = f2bf(arow[c]);
    s_n0[nr*136 + c] = f2bf(nrow[c]);
    #pragma unroll
    for (int i = 0; i < 3; ++i){
      s_a1[i][nr*136 + c] = f2bf(arow[128 + 3*c + i]);
      s_n1[i][nr*136 + c] = f2bf(nrow[128 + 3*c + i]);
    }
  }
  __syncthreads();
  int m15 = lane & 15, quad = lane >> 4;
  int aoff = m15*136 + (quad << 3);
  #pragma unroll
  for (int i8 = 0; i8 < 8; ++i8){
    int tt = wave*8 + i8;
    const u16 *Ag, *An, *Bg, *Bn;
    int dt, vi = 0;
    bool scalar = (tt < 8);
    if (scalar){ dt = tt; Ag = s_a0; An = s_n0; Bg = wsw; Bn = wsw + 2*16384; }
    else { vi = (tt - 8) >> 3; dt = (tt - 8) & 7; Ag = s_a1[vi]; An = s_n1[vi]; Bg = wsw + 16384; Bn = wsw + 3*16384; }
    f32x4 acc = {0.f,0.f,0.f,0.f};
    #pragma unroll
    for (int ks = 0; ks < 4; ++ks){
      Frag a, b;
      a.u4 = *(const uint4*)(Ag + aoff + ks*32);
      b.u4 = *(const uint4*)(Bg + ((size_t)(dt*4 + ks)*64 + lane)*8);
      acc = __builtin_amdgcn_mfma_f32_16x16x32_bf16(a.bf, b.bf, acc, 0, 0, 0);
    }
    #pragma unroll
    for (int ks = 0; ks < 4; ++ks){
      Frag a, b;
      a.u4 = *(const uint4*)(An + aoff + ks*32);
      b.u4 = *(const uint4*)(Bn + ((size_t)(dt*4 + ks)*64 + lane)*8);
      acc = __builtin_amdgcn_mfma_f32_16x16x32_bf16(a.bf, b.bf, acc, 0, 0, 0);
    }
    int d = dt*16 + m15;
    int idx = scalar ? d : (128 + 3*d + vi);
    #pragma unroll
    for (int r = 0; r < 4; ++r){
      int nd = n0b + quad*4 + r;
      float val = acc[r]*LIN_SCALE + out[(size_t)nd*512 + idx];
      out[(size_t)nd*512 + idx] = val;
    }
  }
}

extern "C" void kernel_launch(void* const* d_in, const int* in_sizes, int n_in,
                              void* d_out, int out_size, void* d_ws, size_t ws_size,
                              hipStream_t stream){
  (void)in_sizes; (void)n_in; (void)out_size; (void)ws_size;
  const float* nf    = (const float*)d_in[0];
  const float* ef    = (const float*)d_in[1];
  const float* attrs = (const float*)d_in[2];
  const float* emb   = (const float*)d_in[3];
  const int* snd     = (const int*)d_in[4];
  const int* rcv     = (const int*)d_in[5];
  const float* Wm1   = (const float*)d_in[6];
  const float* Wm2   = (const float*)d_in[7];
  const float* Wm3   = (const float*)d_in[8];
  const float* Wm4   = (const float*)d_in[9];
  const float* rW0   = (const float*)d_in[10];
  const float* rW1   = (const float*)d_in[11];
  const float* sW0   = (const float*)d_in[12];
  const float* sW1   = (const float*)d_in[13];
  char* ws  = (char*)d_ws;
  u16* h3    = (u16*)(ws + H3_OFF);
  u16* wm4s  = (u16*)(ws + WM4_OFF);
  u16* wsw   = (u16*)(ws + WSW_OFF);
  int* cnt   = (int*)(ws + CNT_OFF);
  int* roff  = (int*)(ws + ROFF_OFF);
  int* cur   = (int*)(ws + CUR_OFF);
  int* elist = (int*)(ws + EL_OFF);
  float* out = (float*)d_out;

  prep_weights<<<dim3(80), dim3(256), 0, stream>>>(Wm4, rW0, rW1, sW0, sW1, wm4s, wsw);
  csr_zero<<<dim3(40), dim3(256), 0, stream>>>(cnt);
  csr_count<<<dim3((NE + 255)/256), dim3(256), 0, stream>>>(rcv, cnt);
  csr_scan<<<dim3(1), dim3(256), 0, stream>>>(cnt, roff, cur);
  csr_scatter<<<dim3((NE + 255)/256), dim3(256), 0, stream>>>(rcv, cur, elist);
  radial_h3_kernel<<<dim3(NE/64), dim3(256), 0, stream>>>(emb, Wm1, Wm2, Wm3, h3);
  edge_msg_gather<<<dim3(NN), dim3(256), 0, stream>>>(nf, ef, attrs, snd, h3, wm4s, roff, elist, out);
  out_kernel<<<dim3(NN/16), dim3(256), 0, stream>>>(nf, wsw, out);
}

// Round 3
// 680.037 us; speedup vs baseline: 1.2022x; 1.2022x over previous
//
#include <hip/hip_runtime.h>

#define NN 10000
#define NE 160000

typedef unsigned short u16;
typedef __bf16 bf16x8 __attribute__((ext_vector_type(8)));
typedef float f32x4 __attribute__((ext_vector_type(4)));

#define INV_SQRT3 0.57735026918962576451f
#define INV_SQRT2 0.70710678118654752440f
#define LIN_SCALE 0.08838834764831845f

// ws layout
#define H3_OFF    0                  // E*64 bf16 = 20,480,000 B
#define WM4_OFF   20480000           // 40960 u16 = 81,920 B
#define WSW_OFF   20561920           // 4 * 16384 u16 = 131,072 B
#define CNT_OFF   20692992           // 10240 int
#define ROFF_OFF  20733952           // 10001 int (padded)
#define CUR_OFF   20774912           // 10000 int (padded)
#define EL_OFF    20815872           // 160000 int -> end 21,455,872 B

__device__ __forceinline__ u16 f2bf(float f){
  union { float f; unsigned u; } v; v.f = f;
  unsigned r = v.u + 0x7fffu + ((v.u >> 16) & 1u);
  return (u16)(r >> 16);
}
__device__ __forceinline__ float silu_f(float x){
  return x / (1.f + __expf(-x));
}

union Frag { uint4 u4; bf16x8 bf; };

// ---------------------------------------------------------------- P0: weight swizzle (fp32 -> bf16 B-fragments)
__global__ __launch_bounds__(256) void prep_weights(
    const float* __restrict__ Wm4, const float* __restrict__ rW0, const float* __restrict__ rW1,
    const float* __restrict__ sW0, const float* __restrict__ sW1,
    u16* __restrict__ wm4s, u16* __restrict__ wsw){
  int t  = blockIdx.x * blockDim.x + threadIdx.x;
  int nt = gridDim.x * blockDim.x;
  for (int idx = t; idx < 40960; idx += nt){           // Wm4: (64,640), 40 ct x 2 ks
    int jj = idx & 7; int lane = (idx >> 3) & 63; int blk = idx >> 9;
    int ks = blk & 1; int ct = blk >> 1;
    int k = ks*32 + ((lane >> 4) << 3) + jj;
    int col = ct*16 + (lane & 15);
    wm4s[idx] = f2bf(Wm4[k*640 + col]);
  }
  const float* Ws[4] = { rW0, rW1, sW0, sW1 };
  for (int m = 0; m < 4; ++m){
    const float* src = Ws[m];
    u16* dst = wsw + m*16384;
    for (int idx = t; idx < 16384; idx += nt){         // (128,128), 8 ct x 4 ks
      int jj = idx & 7; int lane = (idx >> 3) & 63; int blk = idx >> 9;
      int ks = blk & 3; int ct = blk >> 2;
      int k = ks*32 + ((lane >> 4) << 3) + jj;
      int col = ct*16 + (lane & 15);
      dst[idx] = f2bf(src[k*128 + col]);
    }
  }
}

// ---------------------------------------------------------------- CSR build (counting sort by receiver)
__global__ __launch_bounds__(256) void csr_zero(int* __restrict__ cnt){
  int t = blockIdx.x * blockDim.x + threadIdx.x;
  if (t < 10240) cnt[t] = 0;
}

__global__ __launch_bounds__(256) void csr_count(const int* __restrict__ rcv, int* __restrict__ cnt){
  int e = blockIdx.x * blockDim.x + threadIdx.x;
  if (e < NE) atomicAdd(&cnt[rcv[e]], 1);
}

__global__ __launch_bounds__(256) void csr_scan(const int* __restrict__ cnt,
                                                int* __restrict__ roff, int* __restrict__ cur){
  __shared__ int s_part[256];
  int t = threadIdx.x;
  int base = t * 40;                      // 256*40 = 10240 >= NN
  int local = 0;
  for (int i = 0; i < 40; ++i){
    int idx = base + i;
    local += (idx < NN) ? cnt[idx] : 0;
  }
  s_part[t] = local;
  __syncthreads();
  for (int d = 1; d < 256; d <<= 1){      // inclusive Hillis-Steele
    int v = (t >= d) ? s_part[t - d] : 0;
    __syncthreads();
    s_part[t] += v;
    __syncthreads();
  }
  int run = (t == 0) ? 0 : s_part[t - 1];
  for (int i = 0; i < 40; ++i){
    int idx = base + i;
    if (idx < NN){
      roff[idx] = run;
      cur[idx]  = run;
      run += cnt[idx];
    }
  }
  if (t == 0) roff[NN] = NE;
}

__global__ __launch_bounds__(256) void csr_scatter(const int* __restrict__ rcv,
                                                   int* __restrict__ cur, int* __restrict__ elist){
  int e = blockIdx.x * blockDim.x + threadIdx.x;
  if (e < NE){
    int r = rcv[e];
    int p = atomicAdd(&cur[r], 1);
    elist[p] = e;
  }
}

// ---------------------------------------------------------------- K0: zero agg (= d_out)
__global__ __launch_bounds__(256) void zero_agg(float* __restrict__ agg){
  int t = blockIdx.x * blockDim.x + threadIdx.x;
  f32x4* p = (f32x4*)agg;
  const int n4 = NN*512/4;
  for (int i = t; i < n4; i += gridDim.x * blockDim.x){
    f32x4 z = {0.f,0.f,0.f,0.f}; p[i] = z;
  }
}

// ---------------------------------------------------------------- K1: h3 = silu(silu(silu(e@Wm1)@Wm2)@Wm3), bf16 out
__global__ __launch_bounds__(256) void radial_h3_kernel(
    const float* __restrict__ emb, const float* __restrict__ Wm1,
    const float* __restrict__ Wm2, const float* __restrict__ Wm3,
    u16* __restrict__ h3){
  __shared__ float s_emb[64*12];
  __shared__ float s_w1[8*64];
  __shared__ float s_w2[64*68];
  __shared__ float s_w3[64*68];
  __shared__ float s_ha[64*65];
  __shared__ float s_hb[64*65];
  int t = threadIdx.x;
  int e0 = blockIdx.x * 64;
  if (t < 64){
    const float4* src = (const float4*)(emb + (size_t)(e0 + t)*8);
    float4 v0 = src[0], v1 = src[1];
    float* r = s_emb + t*12;
    r[0]=v0.x; r[1]=v0.y; r[2]=v0.z; r[3]=v0.w;
    r[4]=v1.x; r[5]=v1.y; r[6]=v1.z; r[7]=v1.w;
  }
  for (int idx = t; idx < 512; idx += 256) s_w1[idx] = Wm1[idx];
  for (int idx = t; idx < 4096; idx += 256){
    int k = idx >> 6, d = idx & 63;
    s_w2[k*68 + d] = Wm2[idx];
    s_w3[k*68 + d] = Wm3[idx];
  }
  __syncthreads();
  int p  = t >> 3;       // 0..31 -> edges 2p, 2p+1
  int dg = t & 7;        // outputs dg*8 .. dg*8+7
  int ea = 2*p, eb = 2*p + 1;
  float acc0[8], acc1[8];
  // layer 1 (K=8)
  #pragma unroll
  for (int j = 0; j < 8; ++j){ acc0[j]=0.f; acc1[j]=0.f; }
  #pragma unroll
  for (int k = 0; k < 8; ++k){
    float h0 = s_emb[ea*12 + k], h1 = s_emb[eb*12 + k];
    #pragma unroll
    for (int j = 0; j < 8; ++j){
      float wv = s_w1[k*64 + dg*8 + j];
      acc0[j] = fmaf(h0, wv, acc0[j]); acc1[j] = fmaf(h1, wv, acc1[j]);
    }
  }
  #pragma unroll
  for (int j = 0; j < 8; ++j){
    s_ha[ea*65 + dg*8 + j] = silu_f(acc0[j]);
    s_ha[eb*65 + dg*8 + j] = silu_f(acc1[j]);
  }
  __syncthreads();
  // layer 2 (K=64)
  #pragma unroll
  for (int j = 0; j < 8; ++j){ acc0[j]=0.f; acc1[j]=0.f; }
  #pragma unroll 4
  for (int k = 0; k < 64; ++k){
    float h0 = s_ha[ea*65 + k], h1 = s_ha[eb*65 + k];
    float wv[8];
    *(f32x4*)&wv[0] = *(const f32x4*)&s_w2[k*68 + dg*8];
    *(f32x4*)&wv[4] = *(const f32x4*)&s_w2[k*68 + dg*8 + 4];
    #pragma unroll
    for (int j = 0; j < 8; ++j){
      acc0[j] = fmaf(h0, wv[j], acc0[j]); acc1[j] = fmaf(h1, wv[j], acc1[j]);
    }
  }
  #pragma unroll
  for (int j = 0; j < 8; ++j){
    s_hb[ea*65 + dg*8 + j] = silu_f(acc0[j]);
    s_hb[eb*65 + dg*8 + j] = silu_f(acc1[j]);
  }
  __syncthreads();
  // layer 3 (K=64) -> global bf16
  #pragma unroll
  for (int j = 0; j < 8; ++j){ acc0[j]=0.f; acc1[j]=0.f; }
  #pragma unroll 4
  for (int k = 0; k < 64; ++k){
    float h0 = s_hb[ea*65 + k], h1 = s_hb[eb*65 + k];
    float wv[8];
    *(f32x4*)&wv[0] = *(const f32x4*)&s_w3[k*68 + dg*8];
    *(f32x4*)&wv[4] = *(const f32x4*)&s_w3[k*68 + dg*8 + 4];
    #pragma unroll
    for (int j = 0; j < 8; ++j){
      acc0[j] = fmaf(h0, wv[j], acc0[j]); acc1[j] = fmaf(h1, wv[j], acc1[j]);
    }
  }
  union { u16 s[8]; uint4 v; } o0, o1;
  #pragma unroll
  for (int j = 0; j < 8; ++j){
    o0.s[j] = f2bf(silu_f(acc0[j]));
    o1.s[j] = f2bf(silu_f(acc1[j]));
  }
  *(uint4*)(h3 + (size_t)(e0 + ea)*64 + dg*8) = o0.v;
  *(uint4*)(h3 + (size_t)(e0 + eb)*64 + dg*8) = o1.v;
}

// ---------------------------------------------------------------- K2: fused w-GEMM + message + SEGMENTED scatter
// one block = 16 CSR-SORTED edges (runs of equal receiver); w-GEMM via MFMA into s_w;
// messages to registers; s_w reused as message buffer; per-thread segmented scan over
// the 16 rows emits ONE contiguous atomic row-add per receiver-run (~2 per block).
__global__ __launch_bounds__(256) void edge_msg_kernel(
    const float* __restrict__ nf, const float* __restrict__ ef, const float* __restrict__ attrs,
    const int* __restrict__ snd, const int* __restrict__ rcv,
    const u16* __restrict__ h3, const u16* __restrict__ wm4s,
    const int* __restrict__ elist, float* __restrict__ agg){
  __shared__ float s_w[16*650];     // 41.6 KB: w (16 x 640) during GEMM, reused as msg buf (16 x 520)
  __shared__ int s_eid[16];
  __shared__ int s_rcv[16];
  int t = threadIdx.x;
  int lane = t & 63, wave = t >> 6;
  int e0 = blockIdx.x << 4;
  if (t < 16){
    int eg = elist[e0 + t];
    s_eid[t] = eg;
    s_rcv[t] = rcv[eg];
  }
  __syncthreads();
  // MFMA: w[16][640] = h3_tile[16][64] @ Wm4[64][640]; each wave: 10 col-tiles
  Frag a0f, a1f;
  const u16* h3r = h3 + (size_t)s_eid[lane & 15]*64 + ((lane >> 4) << 3);
  a0f.u4 = *(const uint4*)(h3r);
  a1f.u4 = *(const uint4*)(h3r + 32);
  int colb = lane & 15;
  int rowb = (lane >> 4) << 2;
  #pragma unroll
  for (int i = 0; i < 10; ++i){
    int ct = wave*10 + i;
    const u16* bp = wm4s + ((size_t)ct*128 + lane)*8;
    Frag b0f, b1f;
    b0f.u4 = *(const uint4*)(bp);
    b1f.u4 = *(const uint4*)(bp + 512);
    f32x4 acc = {0.f,0.f,0.f,0.f};
    acc = __builtin_amdgcn_mfma_f32_16x16x32_bf16(a0f.bf, b0f.bf, acc, 0, 0, 0);
    acc = __builtin_amdgcn_mfma_f32_16x16x32_bf16(a1f.bf, b1f.bf, acc, 0, 0, 0);
    int cb = ct*16 + colb;
    #pragma unroll
    for (int r = 0; r < 4; ++r) s_w[(rowb + r)*650 + cb] = acc[r];
  }
  __syncthreads();
  // messages into registers: 16 threads per edge
  int er = t >> 4, l16 = t & 15;
  int eg = s_eid[er];
  int si = snd[eg], ri = s_rcv[er];
  float4 at = *(const float4*)(attrs + (size_t)eg*4);
  float sh0 = at.x, s1x = at.y, s1y = at.z, s1z = at.w;
  const float* ps = nf + (size_t)si*512;
  const float* pr = nf + (size_t)ri*512;
  const float* pe = ef + (size_t)eg*512;
  const float* wr = s_w + er*650;
  float m0[8], m1x[8], m1y[8], m1z[8];
  #pragma unroll
  for (int j = 0; j < 8; ++j){
    int c = j*16 + l16;
    float x0 = ps[c] + pr[c] + pe[c];
    int vb = 128 + 3*c;
    float xa = ps[vb]   + pr[vb]   + pe[vb];
    float xv = ps[vb+1] + pr[vb+1] + pe[vb+1];
    float xc = ps[vb+2] + pr[vb+2] + pe[vb+2];
    float w0 = wr[c], w1 = wr[128 + c], w2 = wr[256 + c], w3 = wr[384 + c], w4 = wr[512 + c];
    float dot = xa*s1x + xv*s1y + xc*s1z;
    m0[j] = w0*x0*sh0 + w1*dot*INV_SQRT3;
    float cr0 = xv*s1z - xc*s1y;
    float cr1 = xc*s1x - xa*s1z;
    float cr2 = xa*s1y - xv*s1x;
    m1x[j] = w2*xa*sh0 + w3*x0*s1x + w4*cr0*INV_SQRT2;
    m1y[j] = w2*xv*sh0 + w3*x0*s1y + w4*cr1*INV_SQRT2;
    m1z[j] = w2*xc*sh0 + w3*x0*s1z + w4*cr2*INV_SQRT2;
  }
  __syncthreads();            // all reads of s_w (w) done -> safe to overwrite
  // write messages into s_m = s_w reused, row stride 520
  float* mr = s_w + er*520;
  #pragma unroll
  for (int j = 0; j < 8; ++j){
    int c = j*16 + l16;
    int vb = 128 + 3*c;
    mr[c]      = m0[j];
    mr[vb]     = m1x[j];
    mr[vb + 1] = m1y[j];
    mr[vb + 2] = m1z[j];
  }
  __syncthreads();
  // segmented reduce over the 16 rows; one atomic row-add per receiver-run
  float sum0 = 0.f, sum1 = 0.f;
  #pragma unroll
  for (int r = 0; r < 16; ++r){
    sum0 += s_w[r*520 + t];
    sum1 += s_w[r*520 + t + 256];
    if (r == 15 || s_rcv[r] != s_rcv[r + 1]){
      float* ar = agg + (size_t)s_rcv[r]*512;
      unsafeAtomicAdd(ar + t,       sum0);
      unsafeAtomicAdd(ar + t + 256, sum1);
      sum0 = 0.f; sum1 = 0.f;
    }
  }
}

// ---------------------------------------------------------------- K3: out = agg + EL(agg,res) + EL(nf,skip); agg IS out (in-place)
__global__ __launch_bounds__(256) void out_kernel(
    const float* __restrict__ nf, const u16* __restrict__ wsw, float* __restrict__ out){
  __shared__ u16 s_a0[16*136];
  __shared__ u16 s_a1[3][16*136];
  __shared__ u16 s_n0[16*136];
  __shared__ u16 s_n1[3][16*136];
  int t = threadIdx.x;
  int lane = t & 63, wave = t >> 6;
  int n0b = blockIdx.x << 4;
  int nr = t >> 4, l16 = t & 15;
  int node = n0b + nr;
  const float* arow = out + (size_t)node*512;
  const float* nrow = nf  + (size_t)node*512;
  #pragma unroll
  for (int jj = 0; jj < 8; ++jj){
    int c = l16 + jj*16;
    s_a0[nr*136 + c] = f2bf(arow[c]);
    s_n0[nr*136 + c] = f2bf(nrow[c]);
    #pragma unroll
    for (int i = 0; i < 3; ++i){
      s_a1[i][nr*136 + c] = f2bf(arow[128 + 3*c + i]);
      s_n1[i][nr*136 + c] = f2bf(nrow[128 + 3*c + i]);
    }
  }
  __syncthreads();
  int m15 = lane & 15, quad = lane >> 4;
  int aoff = m15*136 + (quad << 3);
  #pragma unroll
  for (int i8 = 0; i8 < 8; ++i8){
    int tt = wave*8 + i8;
    const u16 *Ag, *An, *Bg, *Bn;
    int dt, vi = 0;
    bool scalar = (tt < 8);
    if (scalar){ dt = tt; Ag = s_a0; An = s_n0; Bg = wsw; Bn = wsw + 2*16384; }
    else { vi = (tt - 8) >> 3; dt = (tt - 8) & 7; Ag = s_a1[vi]; An = s_n1[vi]; Bg = wsw + 16384; Bn = wsw + 3*16384; }
    f32x4 acc = {0.f,0.f,0.f,0.f};
    #pragma unroll
    for (int ks = 0; ks < 4; ++ks){
      Frag a, b;
      a.u4 = *(const uint4*)(Ag + aoff + ks*32);
      b.u4 = *(const uint4*)(Bg + ((size_t)(dt*4 + ks)*64 + lane)*8);
      acc = __builtin_amdgcn_mfma_f32_16x16x32_bf16(a.bf, b.bf, acc, 0, 0, 0);
    }
    #pragma unroll
    for (int ks = 0; ks < 4; ++ks){
      Frag a, b;
      a.u4 = *(const uint4*)(An + aoff + ks*32);
      b.u4 = *(const uint4*)(Bn + ((size_t)(dt*4 + ks)*64 + lane)*8);
      acc = __builtin_amdgcn_mfma_f32_16x16x32_bf16(a.bf, b.bf, acc, 0, 0, 0);
    }
    int d = dt*16 + m15;
    int idx = scalar ? d : (128 + 3*d + vi);
    #pragma unroll
    for (int r = 0; r < 4; ++r){
      int nd = n0b + quad*4 + r;
      float val = acc[r]*LIN_SCALE + out[(size_t)nd*512 + idx];
      out[(size_t)nd*512 + idx] = val;
    }
  }
}

extern "C" void kernel_launch(void* const* d_in, const int* in_sizes, int n_in,
                              void* d_out, int out_size, void* d_ws, size_t ws_size,
                              hipStream_t stream){
  (void)in_sizes; (void)n_in; (void)out_size; (void)ws_size;
  const float* nf    = (const float*)d_in[0];
  const float* ef    = (const float*)d_in[1];
  const float* attrs = (const float*)d_in[2];
  const float* emb   = (const float*)d_in[3];
  const int* snd     = (const int*)d_in[4];
  const int* rcv     = (const int*)d_in[5];
  const float* Wm1   = (const float*)d_in[6];
  const float* Wm2   = (const float*)d_in[7];
  const float* Wm3   = (const float*)d_in[8];
  const float* Wm4   = (const float*)d_in[9];
  const float* rW0   = (const float*)d_in[10];
  const float* rW1   = (const float*)d_in[11];
  const float* sW0   = (const float*)d_in[12];
  const float* sW1   = (const float*)d_in[13];
  char* ws  = (char*)d_ws;
  u16* h3    = (u16*)(ws + H3_OFF);
  u16* wm4s  = (u16*)(ws + WM4_OFF);
  u16* wsw   = (u16*)(ws + WSW_OFF);
  int* cnt   = (int*)(ws + CNT_OFF);
  int* roff  = (int*)(ws + ROFF_OFF);
  int* cur   = (int*)(ws + CUR_OFF);
  int* elist = (int*)(ws + EL_OFF);
  float* out = (float*)d_out;

  prep_weights<<<dim3(80), dim3(256), 0, stream>>>(Wm4, rW0, rW1, sW0, sW1, wm4s, wsw);
  csr_zero<<<dim3(40), dim3(256), 0, stream>>>(cnt);
  csr_count<<<dim3((NE + 255)/256), dim3(256), 0, stream>>>(rcv, cnt);
  csr_scan<<<dim3(1), dim3(256), 0, stream>>>(cnt, roff, cur);
  csr_scatter<<<dim3((NE + 255)/256), dim3(256), 0, stream>>>(rcv, cur, elist);
  zero_agg<<<dim3(1280), dim3(256), 0, stream>>>(out);
  radial_h3_kernel<<<dim3(NE/64), dim3(256), 0, stream>>>(emb, Wm1, Wm2, Wm3, h3);
  edge_msg_kernel<<<dim3(NE/16), dim3(256), 0, stream>>>(nf, ef, attrs, snd, rcv, h3, wm4s, elist, out);
  out_kernel<<<dim3(NN/16), dim3(256), 0, stream>>>(nf, wsw, out);
}

// Round 4
// 634.410 us; speedup vs baseline: 1.2887x; 1.0719x over previous
//
#include <hip/hip_runtime.h>

#define NN 10000
#define NE 160000

typedef unsigned short u16;
typedef __bf16 bf16x8 __attribute__((ext_vector_type(8)));
typedef float f32x4 __attribute__((ext_vector_type(4)));

#define INV_SQRT3 0.57735026918962576451f
#define INV_SQRT2 0.70710678118654752440f
#define LIN_SCALE 0.08838834764831845f

// ws layout
#define H3_OFF    0                  // 10000 tiles * 2048 B (h3 in A-fragment order) = 20,480,000 B
#define WM4_OFF   20480000           // 40960 u16 = 81,920 B
#define WSW_OFF   20561920           // 4 * 16384 u16 = 131,072 B
#define CNT_OFF   20692992           // 10240 int
#define ROFF_OFF  20733952           // 10001 int (padded)
#define CUR_OFF   20774912           // 10000 int (padded)
#define EL_OFF    20815872           // 160000 int
#define W1F_OFF   21455872           // 2048 u16 = 4096 B
#define W2F_OFF   21459968           // 4096 u16 = 8192 B
#define W3F_OFF   21468160           // 4096 u16 = 8192 B -> end 21,476,352

__device__ __forceinline__ u16 f2bf(float f){
  union { float f; unsigned u; } v; v.f = f;
  unsigned r = v.u + 0x7fffu + ((v.u >> 16) & 1u);
  return (u16)(r >> 16);
}
__device__ __forceinline__ float silu_f(float x){
  return x / (1.f + __expf(-x));
}

union Frag { uint4 u4; bf16x8 bf; };

// ---------------------------------------------------------------- P0: weight swizzle (fp32 -> bf16 B-fragments) + cnt zero
// B-fragment order for mfma_f32_16x16x32_bf16: element(lane,jj) = W[k][col],
// k = ks*32 + (lane>>4)*8 + jj, col = ct*16 + (lane&15)
__global__ __launch_bounds__(256) void prep_weights(
    const float* __restrict__ Wm4, const float* __restrict__ rW0, const float* __restrict__ rW1,
    const float* __restrict__ sW0, const float* __restrict__ sW1,
    const float* __restrict__ Wm1, const float* __restrict__ Wm2, const float* __restrict__ Wm3,
    u16* __restrict__ wm4s, u16* __restrict__ wsw,
    u16* __restrict__ w1f, u16* __restrict__ w2f, u16* __restrict__ w3f,
    int* __restrict__ cnt){
  int t  = blockIdx.x * blockDim.x + threadIdx.x;
  int nt = gridDim.x * blockDim.x;
  if (t < 10240) cnt[t] = 0;
  for (int idx = t; idx < 40960; idx += nt){           // Wm4: (64,640), 40 ct x 2 ks
    int jj = idx & 7; int lane = (idx >> 3) & 63; int blk = idx >> 9;
    int ks = blk & 1; int ct = blk >> 1;
    int k = ks*32 + ((lane >> 4) << 3) + jj;
    int col = ct*16 + (lane & 15);
    wm4s[idx] = f2bf(Wm4[k*640 + col]);
  }
  for (int idx = t; idx < 2048; idx += nt){            // Wm1: (8,64) zero-padded K->32, 4 ct
    int jj = idx & 7; int lane = (idx >> 3) & 63; int ct = idx >> 9;
    int k = ((lane >> 4) << 3) + jj;
    int col = ct*16 + (lane & 15);
    w1f[idx] = (k < 8) ? f2bf(Wm1[k*64 + col]) : (u16)0;
  }
  for (int idx = t; idx < 4096; idx += nt){            // Wm2/Wm3: (64,64), blk = ct*2+ks
    int jj = idx & 7; int lane = (idx >> 3) & 63; int blk = idx >> 9;
    int ks = blk & 1; int ct = blk >> 1;
    int k = ks*32 + ((lane >> 4) << 3) + jj;
    int col = ct*16 + (lane & 15);
    w2f[idx] = f2bf(Wm2[k*64 + col]);
    w3f[idx] = f2bf(Wm3[k*64 + col]);
  }
  const float* Ws[4] = { rW0, rW1, sW0, sW1 };
  for (int m = 0; m < 4; ++m){
    const float* src = Ws[m];
    u16* dst = wsw + m*16384;
    for (int idx = t; idx < 16384; idx += nt){         // (128,128), 8 ct x 4 ks
      int jj = idx & 7; int lane = (idx >> 3) & 63; int blk = idx >> 9;
      int ks = blk & 3; int ct = blk >> 2;
      int k = ks*32 + ((lane >> 4) << 3) + jj;
      int col = ct*16 + (lane & 15);
      dst[idx] = f2bf(src[k*128 + col]);
    }
  }
}

// ---------------------------------------------------------------- CSR build (counting sort by receiver)
__global__ __launch_bounds__(256) void csr_count(const int* __restrict__ rcv, int* __restrict__ cnt){
  int e = blockIdx.x * blockDim.x + threadIdx.x;
  if (e < NE) atomicAdd(&cnt[rcv[e]], 1);
}

__global__ __launch_bounds__(256) void csr_scan(const int* __restrict__ cnt,
                                                int* __restrict__ roff, int* __restrict__ cur){
  __shared__ int s_part[256];
  int t = threadIdx.x;
  int base = t * 40;                      // 256*40 = 10240 >= NN
  int local = 0;
  for (int i = 0; i < 40; ++i){
    int idx = base + i;
    local += (idx < NN) ? cnt[idx] : 0;
  }
  s_part[t] = local;
  __syncthreads();
  for (int d = 1; d < 256; d <<= 1){      // inclusive Hillis-Steele
    int v = (t >= d) ? s_part[t - d] : 0;
    __syncthreads();
    s_part[t] += v;
    __syncthreads();
  }
  int run = (t == 0) ? 0 : s_part[t - 1];
  for (int i = 0; i < 40; ++i){
    int idx = base + i;
    if (idx < NN){
      roff[idx] = run;
      cur[idx]  = run;
      run += cnt[idx];
    }
  }
  if (t == 0) roff[NN] = NE;
}

__global__ __launch_bounds__(256) void csr_scatter(const int* __restrict__ rcv,
                                                   int* __restrict__ cur, int* __restrict__ elist){
  int e = blockIdx.x * blockDim.x + threadIdx.x;
  if (e < NE){
    int r = rcv[e];
    int p = atomicAdd(&cur[r], 1);
    elist[p] = e;
  }
}

// ---------------------------------------------------------------- K0: zero agg (= d_out)
__global__ __launch_bounds__(256) void zero_agg(float* __restrict__ agg){
  int t = blockIdx.x * blockDim.x + threadIdx.x;
  f32x4* p = (f32x4*)agg;
  const int n4 = NN*512/4;
  for (int i = t; i < n4; i += gridDim.x * blockDim.x){
    f32x4 z = {0.f,0.f,0.f,0.f}; p[i] = z;
  }
}

// ---------------------------------------------------------------- K1: radial MLP via MFMA, bf16 throughout.
// One wave = one 16-edge tile IN ELIST ORDER (tile t == edge_msg block t).
// Output h3f is stored in A-fragment order: h3f[tile][lane][16] = {a0(8), a1(8)}.
// Wave-synchronous LDS transpose between layers (C-layout -> A-fragment), no block barriers.
__global__ __launch_bounds__(256) void radial_mfma_kernel(
    const float* __restrict__ emb, const int* __restrict__ elist,
    const u16* __restrict__ w1f, const u16* __restrict__ w2f, const u16* __restrict__ w3f,
    u16* __restrict__ h3f){
  __shared__ u16 s_w1[2048];
  __shared__ u16 s_w2[4096];
  __shared__ u16 s_w3[4096];
  __shared__ u16 s_h[4][16*72];     // per-wave [16 rows][64 cols], stride 72 u16 (144 B, 16B-aligned)
  int t = threadIdx.x;
  int lane = t & 63, wave = t >> 6;
  for (int i = t; i < 256; i += 256) ((uint4*)s_w1)[i] = ((const uint4*)w1f)[i];
  for (int i = t; i < 512; i += 256) ((uint4*)s_w2)[i] = ((const uint4*)w2f)[i];
  for (int i = t; i < 512; i += 256) ((uint4*)s_w3)[i] = ((const uint4*)w3f)[i];
  __syncthreads();
  int tid = blockIdx.x*4 + wave;
  int l15 = lane & 15, q = lane >> 4;
  u16* sh = s_h[wave];
  // ---- layer 1: A = emb tile (K=8 zero-padded to 32); only q==0 lanes hold data
  Frag a;
  a.u4.x = 0; a.u4.y = 0; a.u4.z = 0; a.u4.w = 0;
  if (q == 0){
    int eid = elist[tid*16 + l15];
    const float* er = emb + (size_t)eid*8;
    float4 v0 = *(const float4*)er;
    float4 v1 = *(const float4*)(er + 4);
    union { u16 s[8]; uint4 v; } pk;
    pk.s[0]=f2bf(v0.x); pk.s[1]=f2bf(v0.y); pk.s[2]=f2bf(v0.z); pk.s[3]=f2bf(v0.w);
    pk.s[4]=f2bf(v1.x); pk.s[5]=f2bf(v1.y); pk.s[6]=f2bf(v1.z); pk.s[7]=f2bf(v1.w);
    a.u4 = pk.v;
  }
  #pragma unroll
  for (int ct = 0; ct < 4; ++ct){
    Frag b; b.u4 = ((const uint4*)s_w1)[ct*64 + lane];
    f32x4 acc = {0.f,0.f,0.f,0.f};
    acc = __builtin_amdgcn_mfma_f32_16x16x32_bf16(a.bf, b.bf, acc, 0, 0, 0);
    #pragma unroll
    for (int r = 0; r < 4; ++r)
      sh[(q*4 + r)*72 + ct*16 + l15] = f2bf(silu_f(acc[r]));
  }
  asm volatile("s_waitcnt lgkmcnt(0)" ::: "memory");
  __builtin_amdgcn_sched_barrier(0);
  // ---- layer 2
  Frag a0, a1;
  a0.u4 = *(const uint4*)(sh + l15*72 + q*8);
  a1.u4 = *(const uint4*)(sh + l15*72 + q*8 + 32);
  float h2[4][4];
  #pragma unroll
  for (int ct = 0; ct < 4; ++ct){
    Frag b0, b1;
    b0.u4 = ((const uint4*)s_w2)[(ct*2 + 0)*64 + lane];
    b1.u4 = ((const uint4*)s_w2)[(ct*2 + 1)*64 + lane];
    f32x4 acc = {0.f,0.f,0.f,0.f};
    acc = __builtin_amdgcn_mfma_f32_16x16x32_bf16(a0.bf, b0.bf, acc, 0, 0, 0);
    acc = __builtin_amdgcn_mfma_f32_16x16x32_bf16(a1.bf, b1.bf, acc, 0, 0, 0);
    #pragma unroll
    for (int r = 0; r < 4; ++r) h2[ct][r] = silu_f(acc[r]);
  }
  #pragma unroll
  for (int ct = 0; ct < 4; ++ct)
    #pragma unroll
    for (int r = 0; r < 4; ++r)
      sh[(q*4 + r)*72 + ct*16 + l15] = f2bf(h2[ct][r]);
  asm volatile("s_waitcnt lgkmcnt(0)" ::: "memory");
  __builtin_amdgcn_sched_barrier(0);
  // ---- layer 3
  a0.u4 = *(const uint4*)(sh + l15*72 + q*8);
  a1.u4 = *(const uint4*)(sh + l15*72 + q*8 + 32);
  float h3v[4][4];
  #pragma unroll
  for (int ct = 0; ct < 4; ++ct){
    Frag b0, b1;
    b0.u4 = ((const uint4*)s_w3)[(ct*2 + 0)*64 + lane];
    b1.u4 = ((const uint4*)s_w3)[(ct*2 + 1)*64 + lane];
    f32x4 acc = {0.f,0.f,0.f,0.f};
    acc = __builtin_amdgcn_mfma_f32_16x16x32_bf16(a0.bf, b0.bf, acc, 0, 0, 0);
    acc = __builtin_amdgcn_mfma_f32_16x16x32_bf16(a1.bf, b1.bf, acc, 0, 0, 0);
    #pragma unroll
    for (int r = 0; r < 4; ++r) h3v[ct][r] = silu_f(acc[r]);
  }
  #pragma unroll
  for (int ct = 0; ct < 4; ++ct)
    #pragma unroll
    for (int r = 0; r < 4; ++r)
      sh[(q*4 + r)*72 + ct*16 + l15] = f2bf(h3v[ct][r]);
  asm volatile("s_waitcnt lgkmcnt(0)" ::: "memory");
  __builtin_amdgcn_sched_barrier(0);
  // ---- emit in A-fragment order: lane's 32 B = {a0(8 u16), a1(8 u16)}
  Frag o0, o1;
  o0.u4 = *(const uint4*)(sh + l15*72 + q*8);
  o1.u4 = *(const uint4*)(sh + l15*72 + q*8 + 32);
  uint4* dst = (uint4*)(h3f + (size_t)tid*1024 + lane*16);
  dst[0] = o0.u4;
  dst[1] = o1.u4;
}

// ---------------------------------------------------------------- K2: fused w-GEMM + message + SEGMENTED scatter
// one block = 16 CSR-SORTED edges (tile blockIdx.x of elist); h3 fragments pre-packed
// by radial_mfma_kernel -> one 32-B coalesced load per lane. Segmented per-run atomics.
__global__ __launch_bounds__(256) void edge_msg_kernel(
    const float* __restrict__ nf, const float* __restrict__ ef, const float* __restrict__ attrs,
    const int* __restrict__ snd, const int* __restrict__ rcv,
    const u16* __restrict__ h3f, const u16* __restrict__ wm4s,
    const int* __restrict__ elist, float* __restrict__ agg){
  __shared__ float s_w[16*650];     // 41.6 KB: w (16 x 640) during GEMM, reused as msg buf (16 x 520)
  __shared__ int s_eid[16];
  __shared__ int s_rcv[16];
  int t = threadIdx.x;
  int lane = t & 63, wave = t >> 6;
  int e0 = blockIdx.x << 4;
  if (t < 16){
    int eg = elist[e0 + t];
    s_eid[t] = eg;
    s_rcv[t] = rcv[eg];
  }
  // MFMA: w[16][640] = h3_tile[16][64] @ Wm4[64][640]; each wave: 10 col-tiles
  Frag a0f, a1f;
  const u16* hp = h3f + (size_t)blockIdx.x*1024 + (size_t)lane*16;
  a0f.u4 = *(const uint4*)(hp);
  a1f.u4 = *(const uint4*)(hp + 8);
  int colb = lane & 15;
  int rowb = (lane >> 4) << 2;
  #pragma unroll
  for (int i = 0; i < 10; ++i){
    int ct = wave*10 + i;
    const u16* bp = wm4s + ((size_t)ct*128 + lane)*8;
    Frag b0f, b1f;
    b0f.u4 = *(const uint4*)(bp);
    b1f.u4 = *(const uint4*)(bp + 512);
    f32x4 acc = {0.f,0.f,0.f,0.f};
    acc = __builtin_amdgcn_mfma_f32_16x16x32_bf16(a0f.bf, b0f.bf, acc, 0, 0, 0);
    acc = __builtin_amdgcn_mfma_f32_16x16x32_bf16(a1f.bf, b1f.bf, acc, 0, 0, 0);
    int cb = ct*16 + colb;
    #pragma unroll
    for (int r = 0; r < 4; ++r) s_w[(rowb + r)*650 + cb] = acc[r];
  }
  __syncthreads();
  // messages into registers: 16 threads per edge
  int er = t >> 4, l16 = t & 15;
  int eg = s_eid[er];
  int si = snd[eg], ri = s_rcv[er];
  float4 at = *(const float4*)(attrs + (size_t)eg*4);
  float sh0 = at.x, s1x = at.y, s1y = at.z, s1z = at.w;
  const float* ps = nf + (size_t)si*512;
  const float* pr = nf + (size_t)ri*512;
  const float* pe = ef + (size_t)eg*512;
  const float* wr = s_w + er*650;
  float m0[8], m1x[8], m1y[8], m1z[8];
  #pragma unroll
  for (int j = 0; j < 8; ++j){
    int c = j*16 + l16;
    float x0 = ps[c] + pr[c] + pe[c];
    int vb = 128 + 3*c;
    float xa = ps[vb]   + pr[vb]   + pe[vb];
    float xv = ps[vb+1] + pr[vb+1] + pe[vb+1];
    float xc = ps[vb+2] + pr[vb+2] + pe[vb+2];
    float w0 = wr[c], w1 = wr[128 + c], w2 = wr[256 + c], w3 = wr[384 + c], w4 = wr[512 + c];
    float dot = xa*s1x + xv*s1y + xc*s1z;
    m0[j] = w0*x0*sh0 + w1*dot*INV_SQRT3;
    float cr0 = xv*s1z - xc*s1y;
    float cr1 = xc*s1x - xa*s1z;
    float cr2 = xa*s1y - xv*s1x;
    m1x[j] = w2*xa*sh0 + w3*x0*s1x + w4*cr0*INV_SQRT2;
    m1y[j] = w2*xv*sh0 + w3*x0*s1y + w4*cr1*INV_SQRT2;
    m1z[j] = w2*xc*sh0 + w3*x0*s1z + w4*cr2*INV_SQRT2;
  }
  __syncthreads();            // all reads of s_w (w) done -> safe to overwrite
  // write messages into s_m = s_w reused, row stride 520
  float* mr = s_w + er*520;
  #pragma unroll
  for (int j = 0; j < 8; ++j){
    int c = j*16 + l16;
    int vb = 128 + 3*c;
    mr[c]      = m0[j];
    mr[vb]     = m1x[j];
    mr[vb + 1] = m1y[j];
    mr[vb + 2] = m1z[j];
  }
  __syncthreads();
  // segmented reduce over the 16 rows; one atomic row-add per receiver-run
  float sum0 = 0.f, sum1 = 0.f;
  #pragma unroll
  for (int r = 0; r < 16; ++r){
    sum0 += s_w[r*520 + t];
    sum1 += s_w[r*520 + t + 256];
    if (r == 15 || s_rcv[r] != s_rcv[r + 1]){
      float* ar = agg + (size_t)s_rcv[r]*512;
      unsafeAtomicAdd(ar + t,       sum0);
      unsafeAtomicAdd(ar + t + 256, sum1);
      sum0 = 0.f; sum1 = 0.f;
    }
  }
}

// ---------------------------------------------------------------- K3: out = agg + EL(agg,res) + EL(nf,skip); agg IS out (in-place)
__global__ __launch_bounds__(256) void out_kernel(
    const float* __restrict__ nf, const u16* __restrict__ wsw, float* __restrict__ out){
  __shared__ u16 s_a0[16*136];
  __shared__ u16 s_a1[3][16*136];
  __shared__ u16 s_n0[16*136];
  __shared__ u16 s_n1[3][16*136];
  int t = threadIdx.x;
  int lane = t & 63, wave = t >> 6;
  int n0b = blockIdx.x << 4;
  int nr = t >> 4, l16 = t & 15;
  int node = n0b + nr;
  const float* arow = out + (size_t)node*512;
  const float* nrow = nf  + (size_t)node*512;
  #pragma unroll
  for (int jj = 0; jj < 8; ++jj){
    int c = l16 + jj*16;
    s_a0[nr*136 + c] = f2bf(arow[c]);
    s_n0[nr*136 + c] = f2bf(nrow[c]);
    #pragma unroll
    for (int i = 0; i < 3; ++i){
      s_a1[i][nr*136 + c] = f2bf(arow[128 + 3*c + i]);
      s_n1[i][nr*136 + c] = f2bf(nrow[128 + 3*c + i]);
    }
  }
  __syncthreads();
  int m15 = lane & 15, quad = lane >> 4;
  int aoff = m15*136 + (quad << 3);
  #pragma unroll
  for (int i8 = 0; i8 < 8; ++i8){
    int tt = wave*8 + i8;
    const u16 *Ag, *An, *Bg, *Bn;
    int dt, vi = 0;
    bool scalar = (tt < 8);
    if (scalar){ dt = tt; Ag = s_a0; An = s_n0; Bg = wsw; Bn = wsw + 2*16384; }
    else { vi = (tt - 8) >> 3; dt = (tt - 8) & 7; Ag = s_a1[vi]; An = s_n1[vi]; Bg = wsw + 16384; Bn = wsw + 3*16384; }
    f32x4 acc = {0.f,0.f,0.f,0.f};
    #pragma unroll
    for (int ks = 0; ks < 4; ++ks){
      Frag a, b;
      a.u4 = *(const uint4*)(Ag + aoff + ks*32);
      b.u4 = *(const uint4*)(Bg + ((size_t)(dt*4 + ks)*64 + lane)*8);
      acc = __builtin_amdgcn_mfma_f32_16x16x32_bf16(a.bf, b.bf, acc, 0, 0, 0);
    }
    #pragma unroll
    for (int ks = 0; ks < 4; ++ks){
      Frag a, b;
      a.u4 = *(const uint4*)(An + aoff + ks*32);
      b.u4 = *(const uint4*)(Bn + ((size_t)(dt*4 + ks)*64 + lane)*8);
      acc = __builtin_amdgcn_mfma_f32_16x16x32_bf16(a.bf, b.bf, acc, 0, 0, 0);
    }
    int d = dt*16 + m15;
    int idx = scalar ? d : (128 + 3*d + vi);
    #pragma unroll
    for (int r = 0; r < 4; ++r){
      int nd = n0b + quad*4 + r;
      float val = acc[r]*LIN_SCALE + out[(size_t)nd*512 + idx];
      out[(size_t)nd*512 + idx] = val;
    }
  }
}

extern "C" void kernel_launch(void* const* d_in, const int* in_sizes, int n_in,
                              void* d_out, int out_size, void* d_ws, size_t ws_size,
                              hipStream_t stream){
  (void)in_sizes; (void)n_in; (void)out_size; (void)ws_size;
  const float* nf    = (const float*)d_in[0];
  const float* ef    = (const float*)d_in[1];
  const float* attrs = (const float*)d_in[2];
  const float* emb   = (const float*)d_in[3];
  const int* snd     = (const int*)d_in[4];
  const int* rcv     = (const int*)d_in[5];
  const float* Wm1   = (const float*)d_in[6];
  const float* Wm2   = (const float*)d_in[7];
  const float* Wm3   = (const float*)d_in[8];
  const float* Wm4   = (const float*)d_in[9];
  const float* rW0   = (const float*)d_in[10];
  const float* rW1   = (const float*)d_in[11];
  const float* sW0   = (const float*)d_in[12];
  const float* sW1   = (const float*)d_in[13];
  char* ws  = (char*)d_ws;
  u16* h3f   = (u16*)(ws + H3_OFF);
  u16* wm4s  = (u16*)(ws + WM4_OFF);
  u16* wsw   = (u16*)(ws + WSW_OFF);
  int* cnt   = (int*)(ws + CNT_OFF);
  int* roff  = (int*)(ws + ROFF_OFF);
  int* cur   = (int*)(ws + CUR_OFF);
  int* elist = (int*)(ws + EL_OFF);
  u16* w1f   = (u16*)(ws + W1F_OFF);
  u16* w2f   = (u16*)(ws + W2F_OFF);
  u16* w3f   = (u16*)(ws + W3F_OFF);
  float* out = (float*)d_out;

  prep_weights<<<dim3(80), dim3(256), 0, stream>>>(Wm4, rW0, rW1, sW0, sW1, Wm1, Wm2, Wm3,
                                                   wm4s, wsw, w1f, w2f, w3f, cnt);
  csr_count<<<dim3((NE + 255)/256), dim3(256), 0, stream>>>(rcv, cnt);
  csr_scan<<<dim3(1), dim3(256), 0, stream>>>(cnt, roff, cur);
  csr_scatter<<<dim3((NE + 255)/256), dim3(256), 0, stream>>>(rcv, cur, elist);
  zero_agg<<<dim3(1280), dim3(256), 0, stream>>>(out);
  radial_mfma_kernel<<<dim3(NE/64), dim3(256), 0, stream>>>(emb, elist, w1f, w2f, w3f, h3f);
  edge_msg_kernel<<<dim3(NE/16), dim3(256), 0, stream>>>(nf, ef, attrs, snd, rcv, h3f, wm4s, elist, out);
  out_kernel<<<dim3(NN/16), dim3(256), 0, stream>>>(nf, wsw, out);
}

// Round 5
// 630.704 us; speedup vs baseline: 1.2963x; 1.0059x over previous
//
#include <hip/hip_runtime.h>

#define NN 10000
#define NE 160000

typedef unsigned short u16;
typedef __bf16 bf16x8 __attribute__((ext_vector_type(8)));
typedef float f32x4 __attribute__((ext_vector_type(4)));

#define INV_SQRT3 0.57735026918962576451f
#define INV_SQRT2 0.70710678118654752440f
#define LIN_SCALE 0.08838834764831845f

// ws layout
#define H3_OFF    0                  // 10000 tiles * 2048 B (h3 in A-fragment order) = 20,480,000 B
#define WM4_OFF   20480000           // 40960 u16 = 81,920 B
#define WSW_OFF   20561920           // 4 * 16384 u16 = 131,072 B
#define CNT_OFF   20692992           // 10240 int
#define ROFF_OFF  20733952           // 10001 int (padded)
#define CUR_OFF   20774912           // 10000 int (padded)
#define EL_OFF    20815872           // 160000 int
#define W1F_OFF   21455872           // 2048 u16 = 4096 B
#define W2F_OFF   21459968           // 4096 u16 = 8192 B
#define W3F_OFF   21468160           // 4096 u16 = 8192 B -> end 21,476,352

__device__ __forceinline__ u16 f2bf(float f){
  union { float f; unsigned u; } v; v.f = f;
  unsigned r = v.u + 0x7fffu + ((v.u >> 16) & 1u);
  return (u16)(r >> 16);
}
__device__ __forceinline__ float silu_f(float x){
  return x / (1.f + __expf(-x));
}

union Frag { uint4 u4; bf16x8 bf; };

// ---------------------------------------------------------------- P0: weight swizzle (fp32 -> bf16 B-fragments) + cnt zero
// B-fragment order for mfma_f32_16x16x32_bf16: element(lane,jj) = W[k][col],
// k = ks*32 + (lane>>4)*8 + jj, col = ct*16 + (lane&15)
__global__ __launch_bounds__(256) void prep_weights(
    const float* __restrict__ Wm4, const float* __restrict__ rW0, const float* __restrict__ rW1,
    const float* __restrict__ sW0, const float* __restrict__ sW1,
    const float* __restrict__ Wm1, const float* __restrict__ Wm2, const float* __restrict__ Wm3,
    u16* __restrict__ wm4s, u16* __restrict__ wsw,
    u16* __restrict__ w1f, u16* __restrict__ w2f, u16* __restrict__ w3f,
    int* __restrict__ cnt){
  int t  = blockIdx.x * blockDim.x + threadIdx.x;
  int nt = gridDim.x * blockDim.x;
  if (t < 10240) cnt[t] = 0;
  for (int idx = t; idx < 40960; idx += nt){           // Wm4: (64,640), 40 ct x 2 ks
    int jj = idx & 7; int lane = (idx >> 3) & 63; int blk = idx >> 9;
    int ks = blk & 1; int ct = blk >> 1;
    int k = ks*32 + ((lane >> 4) << 3) + jj;
    int col = ct*16 + (lane & 15);
    wm4s[idx] = f2bf(Wm4[k*640 + col]);
  }
  for (int idx = t; idx < 2048; idx += nt){            // Wm1: (8,64) zero-padded K->32, 4 ct
    int jj = idx & 7; int lane = (idx >> 3) & 63; int ct = idx >> 9;
    int k = ((lane >> 4) << 3) + jj;
    int col = ct*16 + (lane & 15);
    w1f[idx] = (k < 8) ? f2bf(Wm1[k*64 + col]) : (u16)0;
  }
  for (int idx = t; idx < 4096; idx += nt){            // Wm2/Wm3: (64,64), blk = ct*2+ks
    int jj = idx & 7; int lane = (idx >> 3) & 63; int blk = idx >> 9;
    int ks = blk & 1; int ct = blk >> 1;
    int k = ks*32 + ((lane >> 4) << 3) + jj;
    int col = ct*16 + (lane & 15);
    w2f[idx] = f2bf(Wm2[k*64 + col]);
    w3f[idx] = f2bf(Wm3[k*64 + col]);
  }
  const float* Ws[4] = { rW0, rW1, sW0, sW1 };
  for (int m = 0; m < 4; ++m){
    const float* src = Ws[m];
    u16* dst = wsw + m*16384;
    for (int idx = t; idx < 16384; idx += nt){         // (128,128), 8 ct x 4 ks
      int jj = idx & 7; int lane = (idx >> 3) & 63; int blk = idx >> 9;
      int ks = blk & 3; int ct = blk >> 2;
      int k = ks*32 + ((lane >> 4) << 3) + jj;
      int col = ct*16 + (lane & 15);
      dst[idx] = f2bf(src[k*128 + col]);
    }
  }
}

// ---------------------------------------------------------------- CSR build (counting sort by receiver)
__global__ __launch_bounds__(256) void csr_count(const int* __restrict__ rcv, int* __restrict__ cnt){
  int e = blockIdx.x * blockDim.x + threadIdx.x;
  if (e < NE) atomicAdd(&cnt[rcv[e]], 1);
}

__global__ __launch_bounds__(256) void csr_scan(const int* __restrict__ cnt,
                                                int* __restrict__ roff, int* __restrict__ cur){
  __shared__ int s_part[256];
  int t = threadIdx.x;
  int base = t * 40;                      // 256*40 = 10240 >= NN
  int local = 0;
  for (int i = 0; i < 40; ++i){
    int idx = base + i;
    local += (idx < NN) ? cnt[idx] : 0;
  }
  s_part[t] = local;
  __syncthreads();
  for (int d = 1; d < 256; d <<= 1){      // inclusive Hillis-Steele
    int v = (t >= d) ? s_part[t - d] : 0;
    __syncthreads();
    s_part[t] += v;
    __syncthreads();
  }
  int run = (t == 0) ? 0 : s_part[t - 1];
  for (int i = 0; i < 40; ++i){
    int idx = base + i;
    if (idx < NN){
      roff[idx] = run;
      cur[idx]  = run;
      run += cnt[idx];
    }
  }
  if (t == 0) roff[NN] = NE;
}

// scatter + zero agg (folded; stream order guarantees zero completes before edge_msg)
__global__ __launch_bounds__(256) void csr_scatter(const int* __restrict__ rcv,
                                                   int* __restrict__ cur, int* __restrict__ elist,
                                                   float* __restrict__ agg){
  int e = blockIdx.x * blockDim.x + threadIdx.x;
  if (e < NE){
    int r = rcv[e];
    int p = atomicAdd(&cur[r], 1);
    elist[p] = e;
  }
  f32x4* pz = (f32x4*)agg;
  const int n4 = NN*512/4;
  int nt = gridDim.x * blockDim.x;
  for (int i = e; i < n4; i += nt){
    f32x4 z = {0.f,0.f,0.f,0.f}; pz[i] = z;
  }
}

// ---------------------------------------------------------------- K1: radial MLP via MFMA, bf16 throughout.
// One wave = one 16-edge tile IN ELIST ORDER (tile t == edge_msg block t).
// Output h3f in A-fragment order: h3f[tile][lane][16] = {a0(8), a1(8)}.
__global__ __launch_bounds__(256) void radial_mfma_kernel(
    const float* __restrict__ emb, const int* __restrict__ elist,
    const u16* __restrict__ w1f, const u16* __restrict__ w2f, const u16* __restrict__ w3f,
    u16* __restrict__ h3f){
  __shared__ u16 s_w1[2048];
  __shared__ u16 s_w2[4096];
  __shared__ u16 s_w3[4096];
  __shared__ u16 s_h[4][16*72];     // per-wave [16 rows][64 cols], stride 72 u16
  int t = threadIdx.x;
  int lane = t & 63, wave = t >> 6;
  for (int i = t; i < 256; i += 256) ((uint4*)s_w1)[i] = ((const uint4*)w1f)[i];
  for (int i = t; i < 512; i += 256) ((uint4*)s_w2)[i] = ((const uint4*)w2f)[i];
  for (int i = t; i < 512; i += 256) ((uint4*)s_w3)[i] = ((const uint4*)w3f)[i];
  __syncthreads();
  int tid = blockIdx.x*4 + wave;
  int l15 = lane & 15, q = lane >> 4;
  u16* sh = s_h[wave];
  // ---- layer 1: A = emb tile (K=8 zero-padded to 32); only q==0 lanes hold data
  Frag a;
  a.u4.x = 0; a.u4.y = 0; a.u4.z = 0; a.u4.w = 0;
  if (q == 0){
    int eid = elist[tid*16 + l15];
    const float* er = emb + (size_t)eid*8;
    float4 v0 = *(const float4*)er;
    float4 v1 = *(const float4*)(er + 4);
    union { u16 s[8]; uint4 v; } pk;
    pk.s[0]=f2bf(v0.x); pk.s[1]=f2bf(v0.y); pk.s[2]=f2bf(v0.z); pk.s[3]=f2bf(v0.w);
    pk.s[4]=f2bf(v1.x); pk.s[5]=f2bf(v1.y); pk.s[6]=f2bf(v1.z); pk.s[7]=f2bf(v1.w);
    a.u4 = pk.v;
  }
  #pragma unroll
  for (int ct = 0; ct < 4; ++ct){
    Frag b; b.u4 = ((const uint4*)s_w1)[ct*64 + lane];
    f32x4 acc = {0.f,0.f,0.f,0.f};
    acc = __builtin_amdgcn_mfma_f32_16x16x32_bf16(a.bf, b.bf, acc, 0, 0, 0);
    #pragma unroll
    for (int r = 0; r < 4; ++r)
      sh[(q*4 + r)*72 + ct*16 + l15] = f2bf(silu_f(acc[r]));
  }
  asm volatile("s_waitcnt lgkmcnt(0)" ::: "memory");
  __builtin_amdgcn_sched_barrier(0);
  // ---- layer 2
  Frag a0, a1;
  a0.u4 = *(const uint4*)(sh + l15*72 + q*8);
  a1.u4 = *(const uint4*)(sh + l15*72 + q*8 + 32);
  float h2[4][4];
  #pragma unroll
  for (int ct = 0; ct < 4; ++ct){
    Frag b0, b1;
    b0.u4 = ((const uint4*)s_w2)[(ct*2 + 0)*64 + lane];
    b1.u4 = ((const uint4*)s_w2)[(ct*2 + 1)*64 + lane];
    f32x4 acc = {0.f,0.f,0.f,0.f};
    acc = __builtin_amdgcn_mfma_f32_16x16x32_bf16(a0.bf, b0.bf, acc, 0, 0, 0);
    acc = __builtin_amdgcn_mfma_f32_16x16x32_bf16(a1.bf, b1.bf, acc, 0, 0, 0);
    #pragma unroll
    for (int r = 0; r < 4; ++r) h2[ct][r] = silu_f(acc[r]);
  }
  #pragma unroll
  for (int ct = 0; ct < 4; ++ct)
    #pragma unroll
    for (int r = 0; r < 4; ++r)
      sh[(q*4 + r)*72 + ct*16 + l15] = f2bf(h2[ct][r]);
  asm volatile("s_waitcnt lgkmcnt(0)" ::: "memory");
  __builtin_amdgcn_sched_barrier(0);
  // ---- layer 3
  a0.u4 = *(const uint4*)(sh + l15*72 + q*8);
  a1.u4 = *(const uint4*)(sh + l15*72 + q*8 + 32);
  float h3v[4][4];
  #pragma unroll
  for (int ct = 0; ct < 4; ++ct){
    Frag b0, b1;
    b0.u4 = ((const uint4*)s_w3)[(ct*2 + 0)*64 + lane];
    b1.u4 = ((const uint4*)s_w3)[(ct*2 + 1)*64 + lane];
    f32x4 acc = {0.f,0.f,0.f,0.f};
    acc = __builtin_amdgcn_mfma_f32_16x16x32_bf16(a0.bf, b0.bf, acc, 0, 0, 0);
    acc = __builtin_amdgcn_mfma_f32_16x16x32_bf16(a1.bf, b1.bf, acc, 0, 0, 0);
    #pragma unroll
    for (int r = 0; r < 4; ++r) h3v[ct][r] = silu_f(acc[r]);
  }
  #pragma unroll
  for (int ct = 0; ct < 4; ++ct)
    #pragma unroll
    for (int r = 0; r < 4; ++r)
      sh[(q*4 + r)*72 + ct*16 + l15] = f2bf(h3v[ct][r]);
  asm volatile("s_waitcnt lgkmcnt(0)" ::: "memory");
  __builtin_amdgcn_sched_barrier(0);
  // ---- emit in A-fragment order: lane's 32 B = {a0(8 u16), a1(8 u16)}
  Frag o0, o1;
  o0.u4 = *(const uint4*)(sh + l15*72 + q*8);
  o1.u4 = *(const uint4*)(sh + l15*72 + q*8 + 32);
  uint4* dst = (uint4*)(h3f + (size_t)tid*1024 + lane*16);
  dst[0] = o0.u4;
  dst[1] = o1.u4;
}

// ---------------------------------------------------------------- K2: fused w-GEMM + message + SEGMENTED scatter
// one block = 16 CSR-SORTED edges. comb rows staged via interleaved f32x4 loads held in
// registers across the MFMA GEMM (latency hidden), summed into s_comb; message compute
// is LDS-fed. Segmented per-run atomics unchanged.
__global__ __launch_bounds__(256) void edge_msg_kernel(
    const float* __restrict__ nf, const float* __restrict__ ef, const float* __restrict__ attrs,
    const int* __restrict__ snd, const int* __restrict__ rcv,
    const u16* __restrict__ h3f, const u16* __restrict__ wm4s,
    const int* __restrict__ elist, float* __restrict__ agg){
  __shared__ float s_w[16*650];       // 41.6 KB: w during GEMM, reused as msg buf (16 x 520)
  __shared__ float s_comb[16*524];    // 33.5 KB: comb = nf[s]+nf[r]+ef rows
  __shared__ int s_eid[16];
  __shared__ int s_rcv[16];
  int t = threadIdx.x;
  int lane = t & 63, wave = t >> 6;
  int e0 = blockIdx.x << 4;
  if (t < 16){
    int eg0 = elist[e0 + t];
    s_eid[t] = eg0;
    s_rcv[t] = rcv[eg0];
  }
  __syncthreads();
  int er = t >> 4, l16 = t & 15;
  int eg = s_eid[er];
  int si = snd[eg], ri = s_rcv[er];
  // issue comb loads (interleaved f32x4: lane-consecutive -> 256 B per instr)
  const f32x4* p4s = (const f32x4*)(nf + (size_t)si*512);
  const f32x4* p4r = (const f32x4*)(nf + (size_t)ri*512);
  const f32x4* p4e = (const f32x4*)(ef + (size_t)eg*512);
  f32x4 ca[8], cb[8], cc[8];
  #pragma unroll
  for (int k = 0; k < 8; ++k){
    int p = l16 + 16*k;
    ca[k] = p4s[p]; cb[k] = p4r[p]; cc[k] = p4e[p];
  }
  // MFMA: w[16][640] = h3_tile[16][64] @ Wm4[64][640]; each wave: 10 col-tiles
  Frag a0f, a1f;
  const u16* hp = h3f + (size_t)blockIdx.x*1024 + (size_t)lane*16;
  a0f.u4 = *(const uint4*)(hp);
  a1f.u4 = *(const uint4*)(hp + 8);
  int colb = lane & 15;
  int rowb = (lane >> 4) << 2;
  #pragma unroll
  for (int i = 0; i < 10; ++i){
    int ct = wave*10 + i;
    const u16* bp = wm4s + ((size_t)ct*128 + lane)*8;
    Frag b0f, b1f;
    b0f.u4 = *(const uint4*)(bp);
    b1f.u4 = *(const uint4*)(bp + 512);
    f32x4 acc = {0.f,0.f,0.f,0.f};
    acc = __builtin_amdgcn_mfma_f32_16x16x32_bf16(a0f.bf, b0f.bf, acc, 0, 0, 0);
    acc = __builtin_amdgcn_mfma_f32_16x16x32_bf16(a1f.bf, b1f.bf, acc, 0, 0, 0);
    int cb2 = ct*16 + colb;
    #pragma unroll
    for (int r = 0; r < 4; ++r) s_w[(rowb + r)*650 + cb2] = acc[r];
  }
  // comb sum -> LDS (same add order as before: (ps+pr)+pe)
  #pragma unroll
  for (int k = 0; k < 8; ++k){
    f32x4 s = (ca[k] + cb[k]) + cc[k];
    *(f32x4*)&s_comb[er*524 + (l16 + 16*k)*4] = s;
  }
  __syncthreads();
  // messages into registers: 16 threads per edge, LDS-fed
  float4 at = *(const float4*)(attrs + (size_t)eg*4);
  float sh0 = at.x, s1x = at.y, s1y = at.z, s1z = at.w;
  const float* wr = s_w + er*650;
  const float* cr_ = s_comb + er*524;
  float m0[8], m1x[8], m1y[8], m1z[8];
  #pragma unroll
  for (int j = 0; j < 8; ++j){
    int c = j*16 + l16;
    float x0 = cr_[c];
    int vb = 128 + 3*c;
    float xa = cr_[vb], xv = cr_[vb+1], xc = cr_[vb+2];
    float w0 = wr[c], w1 = wr[128 + c], w2 = wr[256 + c], w3 = wr[384 + c], w4 = wr[512 + c];
    float dot = xa*s1x + xv*s1y + xc*s1z;
    m0[j] = w0*x0*sh0 + w1*dot*INV_SQRT3;
    float cr0 = xv*s1z - xc*s1y;
    float cr1 = xc*s1x - xa*s1z;
    float cr2 = xa*s1y - xv*s1x;
    m1x[j] = w2*xa*sh0 + w3*x0*s1x + w4*cr0*INV_SQRT2;
    m1y[j] = w2*xv*sh0 + w3*x0*s1y + w4*cr1*INV_SQRT2;
    m1z[j] = w2*xc*sh0 + w3*x0*s1z + w4*cr2*INV_SQRT2;
  }
  __syncthreads();            // all reads of s_w (w) done -> safe to overwrite
  float* mr = s_w + er*520;   // msg buffer reuses s_w
  #pragma unroll
  for (int j = 0; j < 8; ++j){
    int c = j*16 + l16;
    int vb = 128 + 3*c;
    mr[c]      = m0[j];
    mr[vb]     = m1x[j];
    mr[vb + 1] = m1y[j];
    mr[vb + 2] = m1z[j];
  }
  __syncthreads();
  // segmented reduce over the 16 rows; one atomic row-add per receiver-run
  float sum0 = 0.f, sum1 = 0.f;
  #pragma unroll
  for (int r = 0; r < 16; ++r){
    sum0 += s_w[r*520 + t];
    sum1 += s_w[r*520 + t + 256];
    if (r == 15 || s_rcv[r] != s_rcv[r + 1]){
      float* ar = agg + (size_t)s_rcv[r]*512;
      unsafeAtomicAdd(ar + t,       sum0);
      unsafeAtomicAdd(ar + t + 256, sum1);
      sum0 = 0.f; sum1 = 0.f;
    }
  }
}

// ---------------------------------------------------------------- K3: out = agg + EL(agg,res) + EL(nf,skip); agg IS out (in-place)
// EL results staged in s_acc (each element written once), then coalesced f32x4 RMW.
__global__ __launch_bounds__(256) void out_kernel(
    const float* __restrict__ nf, const u16* __restrict__ wsw, float* __restrict__ out){
  __shared__ u16 s_a0[16*136];
  __shared__ u16 s_a1[3][16*136];
  __shared__ u16 s_n0[16*136];
  __shared__ u16 s_n1[3][16*136];
  __shared__ float s_acc[16*524];
  int t = threadIdx.x;
  int lane = t & 63, wave = t >> 6;
  int n0b = blockIdx.x << 4;
  int nr = t >> 4, l16 = t & 15;
  int node = n0b + nr;
  const float* arow = out + (size_t)node*512;
  const float* nrow = nf  + (size_t)node*512;
  #pragma unroll
  for (int jj = 0; jj < 8; ++jj){
    int c = l16 + jj*16;
    s_a0[nr*136 + c] = f2bf(arow[c]);
    s_n0[nr*136 + c] = f2bf(nrow[c]);
    #pragma unroll
    for (int i = 0; i < 3; ++i){
      s_a1[i][nr*136 + c] = f2bf(arow[128 + 3*c + i]);
      s_n1[i][nr*136 + c] = f2bf(nrow[128 + 3*c + i]);
    }
  }
  __syncthreads();
  int m15 = lane & 15, quad = lane >> 4;
  int aoff = m15*136 + (quad << 3);
  #pragma unroll
  for (int i8 = 0; i8 < 8; ++i8){
    int tt = wave*8 + i8;
    const u16 *Ag, *An, *Bg, *Bn;
    int dt, vi = 0;
    bool scalar = (tt < 8);
    if (scalar){ dt = tt; Ag = s_a0; An = s_n0; Bg = wsw; Bn = wsw + 2*16384; }
    else { vi = (tt - 8) >> 3; dt = (tt - 8) & 7; Ag = s_a1[vi]; An = s_n1[vi]; Bg = wsw + 16384; Bn = wsw + 3*16384; }
    f32x4 acc = {0.f,0.f,0.f,0.f};
    #pragma unroll
    for (int ks = 0; ks < 4; ++ks){
      Frag a, b;
      a.u4 = *(const uint4*)(Ag + aoff + ks*32);
      b.u4 = *(const uint4*)(Bg + ((size_t)(dt*4 + ks)*64 + lane)*8);
      acc = __builtin_amdgcn_mfma_f32_16x16x32_bf16(a.bf, b.bf, acc, 0, 0, 0);
    }
    #pragma unroll
    for (int ks = 0; ks < 4; ++ks){
      Frag a, b;
      a.u4 = *(const uint4*)(An + aoff + ks*32);
      b.u4 = *(const uint4*)(Bn + ((size_t)(dt*4 + ks)*64 + lane)*8);
      acc = __builtin_amdgcn_mfma_f32_16x16x32_bf16(a.bf, b.bf, acc, 0, 0, 0);
    }
    int d = dt*16 + m15;
    int idx = scalar ? d : (128 + 3*d + vi);
    #pragma unroll
    for (int r = 0; r < 4; ++r)
      s_acc[(quad*4 + r)*524 + idx] = acc[r]*LIN_SCALE;
  }
  __syncthreads();
  // coalesced RMW: 8 x f32x4 per thread over the block's 16 rows
  #pragma unroll
  for (int k = 0; k < 8; ++k){
    int flat4 = t + 256*k;            // 0..2047
    int nd = flat4 >> 7;              // node-local
    int col4 = flat4 & 127;
    f32x4 v = *(const f32x4*)&s_acc[nd*524 + col4*4];
    f32x4* po = (f32x4*)(out + (size_t)(n0b + nd)*512) + col4;
    *po = *po + v;
  }
}

extern "C" void kernel_launch(void* const* d_in, const int* in_sizes, int n_in,
                              void* d_out, int out_size, void* d_ws, size_t ws_size,
                              hipStream_t stream){
  (void)in_sizes; (void)n_in; (void)out_size; (void)ws_size;
  const float* nf    = (const float*)d_in[0];
  const float* ef    = (const float*)d_in[1];
  const float* attrs = (const float*)d_in[2];
  const float* emb   = (const float*)d_in[3];
  const int* snd     = (const int*)d_in[4];
  const int* rcv     = (const int*)d_in[5];
  const float* Wm1   = (const float*)d_in[6];
  const float* Wm2   = (const float*)d_in[7];
  const float* Wm3   = (const float*)d_in[8];
  const float* Wm4   = (const float*)d_in[9];
  const float* rW0   = (const float*)d_in[10];
  const float* rW1   = (const float*)d_in[11];
  const float* sW0   = (const float*)d_in[12];
  const float* sW1   = (const float*)d_in[13];
  char* ws  = (char*)d_ws;
  u16* h3f   = (u16*)(ws + H3_OFF);
  u16* wm4s  = (u16*)(ws + WM4_OFF);
  u16* wsw   = (u16*)(ws + WSW_OFF);
  int* cnt   = (int*)(ws + CNT_OFF);
  int* roff  = (int*)(ws + ROFF_OFF);
  int* cur   = (int*)(ws + CUR_OFF);
  int* elist = (int*)(ws + EL_OFF);
  u16* w1f   = (u16*)(ws + W1F_OFF);
  u16* w2f   = (u16*)(ws + W2F_OFF);
  u16* w3f   = (u16*)(ws + W3F_OFF);
  float* out = (float*)d_out;

  prep_weights<<<dim3(80), dim3(256), 0, stream>>>(Wm4, rW0, rW1, sW0, sW1, Wm1, Wm2, Wm3,
                                                   wm4s, wsw, w1f, w2f, w3f, cnt);
  csr_count<<<dim3((NE + 255)/256), dim3(256), 0, stream>>>(rcv, cnt);
  csr_scan<<<dim3(1), dim3(256), 0, stream>>>(cnt, roff, cur);
  csr_scatter<<<dim3((NE + 255)/256), dim3(256), 0, stream>>>(rcv, cur, elist, out);
  radial_mfma_kernel<<<dim3(NE/64), dim3(256), 0, stream>>>(emb, elist, w1f, w2f, w3f, h3f);
  edge_msg_kernel<<<dim3(NE/16), dim3(256), 0, stream>>>(nf, ef, attrs, snd, rcv, h3f, wm4s, elist, out);
  out_kernel<<<dim3(NN/16), dim3(256), 0, stream>>>(nf, wsw, out);
}